// Round 8
// baseline (161.928 us; speedup 1.0000x reference)
//
#include <hip/hip_runtime.h>
#include <hip/hip_bf16.h>

typedef short s16x8 __attribute__((ext_vector_type(8)));
typedef unsigned u32x4 __attribute__((ext_vector_type(4)));
typedef float f32x4 __attribute__((ext_vector_type(4)));
typedef float f32x2 __attribute__((ext_vector_type(2)));

// f32 -> bf16 bits, round-to-nearest-even (prep kernel only; not hot)
static __device__ __forceinline__ short f2bf(float f) {
    unsigned u = __builtin_bit_cast(unsigned, f);
    unsigned r = (u + 0x7fffu + ((u >> 16) & 1u)) >> 16;
    return (short)r;
}

// packed f32 pair -> 2x bf16 (RNE) in one dword (v_cvt_pk_bf16_f32)
static __device__ __forceinline__ unsigned pk2bf(float a, float b) {
    __hip_bfloat162 h = __float22bfloat162_rn(make_float2(a, b));
    unsigned r;
    __builtin_memcpy(&r, &h, sizeof(r));
    return r;
}

// Pack Wcat = [W1 | W3] (512 x 128) into bf16 B-fragment order with the
// PERMUTED k-order matching contiguous 128B/lane A-loads:
//   MFMA step kk (0..15): c = kk>>2, s = kk&3
//   B slot (lane l = g*16+mB, reg j) holds Wcat[k][n], where
//   k = c*128 + g*32 + s*8 + j   (bijective over (c,g,s,j))
//   n = nt*16 + mB
__global__ void prep_weights(const float* __restrict__ W1,
                             const float* __restrict__ W3,
                             short* __restrict__ bws) {
    int tid = blockIdx.x * blockDim.x + threadIdx.x;   // 0..65535
    int j  = tid & 7;
    int l  = (tid >> 3) & 63;
    int nt = (tid >> 9) & 7;
    int kk = tid >> 12;
    int g  = l >> 4;
    int k = ((kk >> 2) << 7) + (g << 5) + ((kk & 3) << 3) + j;
    int n = nt * 16 + (l & 15);
    float v = (n < 64) ? W1[k * 64 + n] : W3[k * 64 + (n - 64)];
    bws[tid] = f2bf(v);
}

__global__ __launch_bounds__(1024, 4)
void mf2_main(const float* __restrict__ probs, const float* __restrict__ x,
              const short* __restrict__ bws,
              const float* __restrict__ b1, const float* __restrict__ W2,
              const float* __restrict__ b2, const float* __restrict__ b3,
              const float* __restrict__ W4, const float* __restrict__ b4,
              float* __restrict__ out)
{
    __shared__ short bsh[512 * 128];   // 128 KiB: full packed [W1|W3] tile

    const int tid  = threadIdx.x;      // 0..1023 (16 waves)
    const int lane = tid & 63;
    const int wv   = tid >> 6;         // 0..15
    const int g    = lane >> 4;        // 0..3  (k-group: owns k = c*128 + g*32 + [0,32))
    const int m    = lane & 15;        // 0..15 (A-row / C-col)
    const long rowBase = (long)blockIdx.x * 256 + wv * 16;   // 16 rows per wave

    // A loads: lane reads 128 CONTIGUOUS bytes of row (rowBase + m) per c-step:
    // x[row][c*128 + g*32 .. +32)  => 512 B contiguous per row-visit (4 lanes)
    const float* xp = x + (rowBase + m) * 512 + g * 32;

    // ---- preload c=0 raw A BEFORE staging (overlaps barrier drain) ----
    f32x4 ra[2][8];   // [c&1][quad] — statically indexed (c-loop unrolled)
    #pragma unroll
    for (int q = 0; q < 8; ++q)
        ra[0][q] = *((const f32x4*)xp + q);

    // ---- stage packed B into LDS once per block (coalesced, conflict-free) ----
    {
        const f32x4* src = (const f32x4*)bws;   // 8192 x 16B
        f32x4* dst = (f32x4*)bsh;
        #pragma unroll
        for (int it = 0; it < 8; ++it) {
            const int idx = it * 1024 + tid;
            dst[idx] = src[idx];
        }
    }
    __syncthreads();

    const s16x8* bls = (const s16x8*)bsh + lane;

    f32x4 acc[8];
    #pragma unroll
    for (int nt = 0; nt < 8; ++nt)
        acc[nt] = (f32x4){0.f, 0.f, 0.f, 0.f};

    #pragma unroll
    for (int c = 0; c < 4; ++c) {
        // convert the 32 loaded floats -> 4 MFMA A-fragments (s = 0..3)
        s16x8 a[4];
        #pragma unroll
        for (int s = 0; s < 4; ++s) {
            u32x4 pa;
            pa[0] = pk2bf(ra[c & 1][2 * s][0],     ra[c & 1][2 * s][1]);
            pa[1] = pk2bf(ra[c & 1][2 * s][2],     ra[c & 1][2 * s][3]);
            pa[2] = pk2bf(ra[c & 1][2 * s + 1][0], ra[c & 1][2 * s + 1][1]);
            pa[3] = pk2bf(ra[c & 1][2 * s + 1][2], ra[c & 1][2 * s + 1][3]);
            a[s] = __builtin_bit_cast(s16x8, pa);
        }

        // prefetch next c's 128 contiguous bytes (hides HBM under 32 MFMAs)
        if (c < 3) {
            #pragma unroll
            for (int q = 0; q < 8; ++q)
                ra[(c + 1) & 1][q] = *((const f32x4*)(xp + (c + 1) * 128) + q);
        }

        // 4 MFMA sub-steps; B fragments from LDS
        #pragma unroll
        for (int s = 0; s < 4; ++s) {
            const int kk = c * 4 + s;
            #pragma unroll
            for (int nt = 0; nt < 8; ++nt) {
                s16x8 b = bls[kk * 512 + nt * 64];
                acc[nt] = __builtin_amdgcn_mfma_f32_16x16x32_bf16(a[s], b, acc[nt], 0, 0, 0);
            }
        }
    }

    // ---- epilogue (weight/bias loads deferred past the loop) ----
    float w2r[4][4];
    float w4r[4][2];
    float biasr[8];
    #pragma unroll
    for (int nt = 0; nt < 4; ++nt) {
        const int col = m + 16 * nt;
        f32x4 w2v = *(const f32x4*)(W2 + col * 4);
        #pragma unroll
        for (int c = 0; c < 4; ++c) w2r[nt][c] = w2v[c];
        f32x2 w4v = *(const f32x2*)(W4 + col * 2);
        w4r[nt][0] = w4v[0]; w4r[nt][1] = w4v[1];
    }
    #pragma unroll
    for (int nt = 0; nt < 8; ++nt) {
        const int col = m + 16 * nt;
        biasr[nt] = (col < 64) ? b1[col] : b3[col - 64];
    }
    float b2v[4], b4v[2];
    #pragma unroll
    for (int c = 0; c < 4; ++c) b2v[c] = b2[c];
    #pragma unroll
    for (int c = 0; c < 2; ++c) b4v[c] = b4[c];

    // bias+relu, layer-2 partials, 16-lane butterfly reduce.
    // C layout: lane holds row 4*g + r, col m + 16*nt (reg r).
    float own[6] = {0.f, 0.f, 0.f, 0.f, 0.f, 0.f};
    #pragma unroll
    for (int r = 0; r < 4; ++r) {
        float v[6] = {0.f, 0.f, 0.f, 0.f, 0.f, 0.f};
        #pragma unroll
        for (int nt = 0; nt < 4; ++nt) {
            float h = fmaxf(acc[nt][r] + biasr[nt], 0.f);
            v[0] += h * w2r[nt][0];
            v[1] += h * w2r[nt][1];
            v[2] += h * w2r[nt][2];
            v[3] += h * w2r[nt][3];
        }
        #pragma unroll
        for (int j = 0; j < 4; ++j) {
            float h = fmaxf(acc[4 + j][r] + biasr[4 + j], 0.f);
            v[4] += h * w4r[j][0];
            v[5] += h * w4r[j][1];
        }
        #pragma unroll
        for (int msk = 1; msk <= 8; msk <<= 1) {
            #pragma unroll
            for (int c = 0; c < 6; ++c) v[c] += __shfl_xor(v[c], msk, 64);
        }
        if (m == r) {
            #pragma unroll
            for (int c = 0; c < 6; ++c) own[c] = v[c];
        }
    }

    // lanes m<4 finish one row each: sigmoid head + 2-class softmax
    if (m < 4) {
        const long row = rowBase + g * 4 + m;
        f32x4 pr = *(const f32x4*)(probs + row * 4);   // p00 p01 p10 p11
        float mu1[2], mu2[2], icv[2];
        #pragma unroll
        for (int c = 0; c < 2; ++c) {
            mu1[c] = 1.0f / (1.0f + __expf(-(own[c]     + b2v[c])));
            mu2[c] = 1.0f / (1.0f + __expf(-(own[2 + c] + b2v[2 + c])));
            icv[c] = 1.0f / (1.0f + __expf(-(own[4 + c] + b4v[c])));
        }
        float res[2];
        #pragma unroll
        for (int c = 0; c < 2; ++c) {
            float p0 = pr[c], p1 = pr[2 + c];
            float m12 = fminf(fmaxf(mu1[c], mu2[c]) + icv[c], 1.0f);
            res[c] = (p0 <= p1) ? (p0 * mu1[c] + (p1 - p0) * m12)
                                : (p1 * mu2[c] + (p0 - p1) * m12);
        }
        float d01 = res[0] - res[1];
        f32x2 o;
        o[0] = 1.0f / (1.0f + __expf(-d01));
        o[1] = 1.0f / (1.0f + __expf(d01));
        *(f32x2*)(out + row * 2) = o;
    }
}

extern "C" void kernel_launch(void* const* d_in, const int* in_sizes, int n_in,
                              void* d_out, int out_size, void* d_ws, size_t ws_size,
                              hipStream_t stream)
{
    const float* probs = (const float*)d_in[0];
    const float* x     = (const float*)d_in[1];
    const float* W1    = (const float*)d_in[2];
    const float* b1    = (const float*)d_in[3];
    const float* W2    = (const float*)d_in[4];
    const float* b2    = (const float*)d_in[5];
    const float* W3    = (const float*)d_in[6];
    const float* b3    = (const float*)d_in[7];
    const float* W4    = (const float*)d_in[8];
    const float* b4    = (const float*)d_in[9];
    float* out = (float*)d_out;
    short* bws = (short*)d_ws;   // 512*128 bf16 = 128 KiB

    hipLaunchKernelGGL(prep_weights, dim3(256), dim3(256), 0, stream, W1, W3, bws);
    hipLaunchKernelGGL(mf2_main, dim3(1024), dim3(1024), 0, stream,
                       probs, x, bws, b1, W2, b2, b3, W4, b4, out);
}

// Round 9
// 127.169 us; speedup vs baseline: 1.2733x; 1.2733x over previous
//
#include <hip/hip_runtime.h>
#include <hip/hip_bf16.h>

typedef short s16x8 __attribute__((ext_vector_type(8)));
typedef unsigned u32x4 __attribute__((ext_vector_type(4)));
typedef float f32x4 __attribute__((ext_vector_type(4)));
typedef float f32x2 __attribute__((ext_vector_type(2)));

// f32 -> bf16 bits, round-to-nearest-even (prep kernel only; not hot)
static __device__ __forceinline__ short f2bf(float f) {
    unsigned u = __builtin_bit_cast(unsigned, f);
    unsigned r = (u + 0x7fffu + ((u >> 16) & 1u)) >> 16;
    return (short)r;
}

// packed f32 pair -> 2x bf16 (RNE) in one dword (v_cvt_pk_bf16_f32)
static __device__ __forceinline__ unsigned pk2bf(float a, float b) {
    __hip_bfloat162 h = __float22bfloat162_rn(make_float2(a, b));
    unsigned r;
    __builtin_memcpy(&r, &h, sizeof(r));
    return r;
}

// Pack Wcat = [W1 | W3] (512 x 128) into bf16 B-fragment order (R1 mapping):
// bws[((kk*8+nt)*64 + l)*8 + j] = Wcat[kk*32 + 8*(l>>4) + j][nt*16 + (l&15)]
__global__ void prep_weights(const float* __restrict__ W1,
                             const float* __restrict__ W3,
                             short* __restrict__ bws) {
    int tid = blockIdx.x * blockDim.x + threadIdx.x;   // 0..65535
    int j  = tid & 7;
    int l  = (tid >> 3) & 63;
    int nt = (tid >> 9) & 7;
    int kk = tid >> 12;
    int k = kk * 32 + ((l >> 4) << 3) + j;
    int n = nt * 16 + (l & 15);
    float v = (n < 64) ? W1[k * 64 + n] : W3[k * 64 + (n - 64)];
    bws[tid] = f2bf(v);
}

// 512-thread blocks, 64 KiB LDS (half-K B-tile, re-staged mid-block) ->
// TWO blocks co-resident per CU; staging/epilogue of one overlaps the
// other's K-loop. Access pattern identical to the verified R7 kernel.
__global__ __launch_bounds__(512, 4)
void mf2_main(const float* __restrict__ probs, const float* __restrict__ x,
              const short* __restrict__ bws,
              const float* __restrict__ b1, const float* __restrict__ W2,
              const float* __restrict__ b2, const float* __restrict__ b3,
              const float* __restrict__ W4, const float* __restrict__ b4,
              float* __restrict__ out)
{
    __shared__ short bsh[256 * 128];   // 64 KiB: 8 kk-steps of packed [W1|W3]

    const int tid  = threadIdx.x;      // 0..511 (8 waves)
    const int lane = tid & 63;
    const int wv   = tid >> 6;         // 0..7
    const int g    = lane >> 4;        // 0..3  (k-chunk group)
    const int m    = lane & 15;        // 0..15 (A-row / C-col)
    const long rowBase = (long)blockIdx.x * 128 + wv * 16;   // 16 rows per wave

    // A loads: lane reads 8 contiguous f32 of row (rowBase + m), k-chunk 8*g
    // (per instruction: 16 rows x 128 B contiguous segments — best coalescing)
    const float* xp = x + (rowBase + m) * 512 + g * 8;

    // ---- 4-deep prefetch ring: issue kk=0..3 BEFORE staging ----
    f32x4 ra[4][2];   // [ring slot][half] — statically indexed
    #pragma unroll
    for (int p = 0; p < 4; ++p) {
        const float* pp = xp + p * 32;
        ra[p][0] = *(const f32x4*)pp;
        ra[p][1] = *(const f32x4*)(pp + 4);
    }

    // ---- stage K-half 0 (64 KiB) ----
    {
        const f32x4* src = (const f32x4*)bws;   // 8192 x 16B total; 4096 per half
        f32x4* dst = (f32x4*)bsh;
        #pragma unroll
        for (int it = 0; it < 8; ++it) {
            const int idx = it * 512 + tid;
            dst[idx] = src[idx];
        }
    }
    __syncthreads();

    const s16x8* bls = (const s16x8*)bsh + lane;

    f32x4 acc[8];
    #pragma unroll
    for (int nt = 0; nt < 8; ++nt)
        acc[nt] = (f32x4){0.f, 0.f, 0.f, 0.f};

    #pragma unroll
    for (int half = 0; half < 2; ++half) {
        if (half == 1) {
            // re-stage K-half 1 into the same buffer (other resident block
            // keeps the CU busy during these barriers)
            __syncthreads();
            const f32x4* src = (const f32x4*)bws;
            f32x4* dst = (f32x4*)bsh;
            #pragma unroll
            for (int it = 0; it < 8; ++it) {
                const int idx = it * 512 + tid;
                dst[idx] = src[4096 + idx];
            }
            __syncthreads();
        }

        #pragma unroll
        for (int k8 = 0; k8 < 8; ++k8) {
            const int kk = half * 8 + k8;
            const int s = kk & 3;
            // consume ring slot s -> bf16 A fragment
            u32x4 pa;
            pa[0] = pk2bf(ra[s][0][0], ra[s][0][1]);
            pa[1] = pk2bf(ra[s][0][2], ra[s][0][3]);
            pa[2] = pk2bf(ra[s][1][0], ra[s][1][1]);
            pa[3] = pk2bf(ra[s][1][2], ra[s][1][3]);
            s16x8 a = __builtin_bit_cast(s16x8, pa);

            // refill slot s with kk+4 (A-loads independent of B staging)
            if (kk < 12) {
                const float* pp = xp + (kk + 4) * 32;
                ra[s][0] = *(const f32x4*)pp;
                ra[s][1] = *(const f32x4*)(pp + 4);
            }

            #pragma unroll
            for (int nt = 0; nt < 8; ++nt) {
                s16x8 b = bls[k8 * 512 + nt * 64];
                acc[nt] = __builtin_amdgcn_mfma_f32_16x16x32_bf16(a, b, acc[nt], 0, 0, 0);
            }
        }
    }

    // ---- epilogue (weight/bias loads deferred past the loop) ----
    float w2r[4][4];
    float w4r[4][2];
    float biasr[8];
    #pragma unroll
    for (int nt = 0; nt < 4; ++nt) {
        const int col = m + 16 * nt;
        f32x4 w2v = *(const f32x4*)(W2 + col * 4);
        #pragma unroll
        for (int c = 0; c < 4; ++c) w2r[nt][c] = w2v[c];
        f32x2 w4v = *(const f32x2*)(W4 + col * 2);
        w4r[nt][0] = w4v[0]; w4r[nt][1] = w4v[1];
    }
    #pragma unroll
    for (int nt = 0; nt < 8; ++nt) {
        const int col = m + 16 * nt;
        biasr[nt] = (col < 64) ? b1[col] : b3[col - 64];
    }
    float b2v[4], b4v[2];
    #pragma unroll
    for (int c = 0; c < 4; ++c) b2v[c] = b2[c];
    #pragma unroll
    for (int c = 0; c < 2; ++c) b4v[c] = b4[c];

    // bias+relu, layer-2 partials, 16-lane butterfly reduce.
    // C layout: lane holds row 4*g + r, col m + 16*nt (reg r).
    float own[6] = {0.f, 0.f, 0.f, 0.f, 0.f, 0.f};
    #pragma unroll
    for (int r = 0; r < 4; ++r) {
        float v[6] = {0.f, 0.f, 0.f, 0.f, 0.f, 0.f};
        #pragma unroll
        for (int nt = 0; nt < 4; ++nt) {
            float h = fmaxf(acc[nt][r] + biasr[nt], 0.f);
            v[0] += h * w2r[nt][0];
            v[1] += h * w2r[nt][1];
            v[2] += h * w2r[nt][2];
            v[3] += h * w2r[nt][3];
        }
        #pragma unroll
        for (int j = 0; j < 4; ++j) {
            float h = fmaxf(acc[4 + j][r] + biasr[4 + j], 0.f);
            v[4] += h * w4r[j][0];
            v[5] += h * w4r[j][1];
        }
        #pragma unroll
        for (int msk = 1; msk <= 8; msk <<= 1) {
            #pragma unroll
            for (int c = 0; c < 6; ++c) v[c] += __shfl_xor(v[c], msk, 64);
        }
        if (m == r) {
            #pragma unroll
            for (int c = 0; c < 6; ++c) own[c] = v[c];
        }
    }

    // lanes m<4 finish one row each: sigmoid head + 2-class softmax
    if (m < 4) {
        const long row = rowBase + g * 4 + m;
        f32x4 pr = *(const f32x4*)(probs + row * 4);   // p00 p01 p10 p11
        float mu1[2], mu2[2], icv[2];
        #pragma unroll
        for (int c = 0; c < 2; ++c) {
            mu1[c] = 1.0f / (1.0f + __expf(-(own[c]     + b2v[c])));
            mu2[c] = 1.0f / (1.0f + __expf(-(own[2 + c] + b2v[2 + c])));
            icv[c] = 1.0f / (1.0f + __expf(-(own[4 + c] + b4v[c])));
        }
        float res[2];
        #pragma unroll
        for (int c = 0; c < 2; ++c) {
            float p0 = pr[c], p1 = pr[2 + c];
            float m12 = fminf(fmaxf(mu1[c], mu2[c]) + icv[c], 1.0f);
            res[c] = (p0 <= p1) ? (p0 * mu1[c] + (p1 - p0) * m12)
                                : (p1 * mu2[c] + (p0 - p1) * m12);
        }
        float d01 = res[0] - res[1];
        f32x2 o;
        o[0] = 1.0f / (1.0f + __expf(-d01));
        o[1] = 1.0f / (1.0f + __expf(d01));
        *(f32x2*)(out + row * 2) = o;
    }
}

extern "C" void kernel_launch(void* const* d_in, const int* in_sizes, int n_in,
                              void* d_out, int out_size, void* d_ws, size_t ws_size,
                              hipStream_t stream)
{
    const float* probs = (const float*)d_in[0];
    const float* x     = (const float*)d_in[1];
    const float* W1    = (const float*)d_in[2];
    const float* b1    = (const float*)d_in[3];
    const float* W2    = (const float*)d_in[4];
    const float* b2    = (const float*)d_in[5];
    const float* W3    = (const float*)d_in[6];
    const float* b3    = (const float*)d_in[7];
    const float* W4    = (const float*)d_in[8];
    const float* b4    = (const float*)d_in[9];
    float* out = (float*)d_out;
    short* bws = (short*)d_ws;   // 512*128 bf16 = 128 KiB

    hipLaunchKernelGGL(prep_weights, dim3(256), dim3(256), 0, stream, W1, W3, bws);
    hipLaunchKernelGGL(mf2_main, dim3(2048), dim3(512), 0, stream,
                       probs, x, bws, b1, W2, b2, b3, W4, b4, out);
}

// Round 10
// 119.442 us; speedup vs baseline: 1.3557x; 1.0647x over previous
//
#include <hip/hip_runtime.h>
#include <hip/hip_bf16.h>

typedef short s16x8 __attribute__((ext_vector_type(8)));
typedef unsigned u32x4 __attribute__((ext_vector_type(4)));
typedef float f32x4 __attribute__((ext_vector_type(4)));
typedef float f32x2 __attribute__((ext_vector_type(2)));

// f32 -> bf16 bits, round-to-nearest-even (prep kernel only; not hot)
static __device__ __forceinline__ short f2bf(float f) {
    unsigned u = __builtin_bit_cast(unsigned, f);
    unsigned r = (u + 0x7fffu + ((u >> 16) & 1u)) >> 16;
    return (short)r;
}

// packed f32 pair -> 2x bf16 (RNE) in one dword (v_cvt_pk_bf16_f32)
static __device__ __forceinline__ unsigned pk2bf(float a, float b) {
    __hip_bfloat162 h = __float22bfloat162_rn(make_float2(a, b));
    unsigned r;
    __builtin_memcpy(&r, &h, sizeof(r));
    return r;
}

// Pack Wcat = [W1 | W3] (512 x 128) into bf16 B-fragment order (R1 mapping):
// bws[((kk*8+nt)*64 + l)*8 + j] = Wcat[kk*32 + 8*(l>>4) + j][nt*16 + (l&15)]
__global__ void prep_weights(const float* __restrict__ W1,
                             const float* __restrict__ W3,
                             short* __restrict__ bws) {
    int tid = blockIdx.x * blockDim.x + threadIdx.x;   // 0..65535
    int j  = tid & 7;
    int l  = (tid >> 3) & 63;
    int nt = (tid >> 9) & 7;
    int kk = tid >> 12;
    int k = kk * 32 + ((l >> 4) << 3) + j;
    int n = nt * 16 + (l & 15);
    float v = (n < 64) ? W1[k * 64 + n] : W3[k * 64 + (n - 64)];
    bws[tid] = f2bf(v);
}

// R9 geometry (8 waves, 16 rows/wave, 64 KiB half-K B-tile, 2 blocks/CU).
// Single change: A-loads issued in 4-kk BURSTS (8 back-to-back dwordx4 per
// lane covering 512 B of each row) instead of one kk per ring refill —
// concentrates each DRAM page's visits in time.
__global__ __launch_bounds__(512, 4)
void mf2_main(const float* __restrict__ probs, const float* __restrict__ x,
              const short* __restrict__ bws,
              const float* __restrict__ b1, const float* __restrict__ W2,
              const float* __restrict__ b2, const float* __restrict__ b3,
              const float* __restrict__ W4, const float* __restrict__ b4,
              float* __restrict__ out)
{
    __shared__ short bsh[256 * 128];   // 64 KiB: 8 kk-steps of packed [W1|W3]

    const int tid  = threadIdx.x;      // 0..511 (8 waves)
    const int lane = tid & 63;
    const int g    = lane >> 4;        // 0..3  (k-chunk group)
    const int m    = lane & 15;        // 0..15 (A-row / C-col)
    const long rowBase = (long)blockIdx.x * 128 + (tid >> 6) * 16;   // 16 rows/wave

    // A loads: lane reads 8 contiguous f32 of row (rowBase + m), k-chunk 8*g
    const float* xp = x + (rowBase + m) * 512 + g * 8;

    f32x4 ra[4][2];   // raw burst buffer (one 4-kk burst)
    s16x8 af[4];      // converted bf16 fragments for the burst being consumed

    // ---- burst 0 (kk 0..3): 8 back-to-back loads BEFORE staging ----
    #pragma unroll
    for (int p = 0; p < 4; ++p) {
        const float* pp = xp + p * 32;
        ra[p][0] = *(const f32x4*)pp;
        ra[p][1] = *(const f32x4*)(pp + 4);
    }

    // ---- stage K-half 0 (64 KiB) ----
    {
        const f32x4* src = (const f32x4*)bws;
        f32x4* dst = (f32x4*)bsh;
        #pragma unroll
        for (int it = 0; it < 8; ++it) {
            const int idx = it * 512 + tid;
            dst[idx] = src[idx];
        }
    }
    __syncthreads();

    const s16x8* bls = (const s16x8*)bsh + lane;

    f32x4 acc[8];
    #pragma unroll
    for (int nt = 0; nt < 8; ++nt)
        acc[nt] = (f32x4){0.f, 0.f, 0.f, 0.f};

    #pragma unroll
    for (int burst = 0; burst < 4; ++burst) {
        // convert current burst raw -> bf16 fragments (frees ra)
        #pragma unroll
        for (int s = 0; s < 4; ++s) {
            u32x4 pa;
            pa[0] = pk2bf(ra[s][0][0], ra[s][0][1]);
            pa[1] = pk2bf(ra[s][0][2], ra[s][0][3]);
            pa[2] = pk2bf(ra[s][1][0], ra[s][1][1]);
            pa[3] = pk2bf(ra[s][1][2], ra[s][1][3]);
            af[s] = __builtin_bit_cast(s16x8, pa);
        }

        // issue next burst (8 back-to-back loads, 512 B per row) — in flight
        // under the 32-MFMA block below
        if (burst < 3) {
            #pragma unroll
            for (int p = 0; p < 4; ++p) {
                const float* pp = xp + (burst + 1) * 128 + p * 32;
                ra[p][0] = *(const f32x4*)pp;
                ra[p][1] = *(const f32x4*)(pp + 4);
            }
        }

        // mid-block: re-stage B K-half 1 (burst-2 loads remain in flight)
        if (burst == 2) {
            __syncthreads();
            const f32x4* src = (const f32x4*)bws;
            f32x4* dst = (f32x4*)bsh;
            #pragma unroll
            for (int it = 0; it < 8; ++it) {
                const int idx = it * 512 + tid;
                dst[idx] = src[4096 + idx];
            }
            __syncthreads();
        }

        // 4 MFMA sub-steps for this burst; B fragments from LDS
        #pragma unroll
        for (int s = 0; s < 4; ++s) {
            const int k8 = (burst & 1) * 4 + s;   // kk within current B half
            #pragma unroll
            for (int nt = 0; nt < 8; ++nt) {
                s16x8 b = bls[k8 * 512 + nt * 64];
                acc[nt] = __builtin_amdgcn_mfma_f32_16x16x32_bf16(af[s], b, acc[nt], 0, 0, 0);
            }
        }
    }

    // ---- epilogue (weight/bias loads deferred past the loop) ----
    float w2r[4][4];
    float w4r[4][2];
    float biasr[8];
    #pragma unroll
    for (int nt = 0; nt < 4; ++nt) {
        const int col = m + 16 * nt;
        f32x4 w2v = *(const f32x4*)(W2 + col * 4);
        #pragma unroll
        for (int c = 0; c < 4; ++c) w2r[nt][c] = w2v[c];
        f32x2 w4v = *(const f32x2*)(W4 + col * 2);
        w4r[nt][0] = w4v[0]; w4r[nt][1] = w4v[1];
    }
    #pragma unroll
    for (int nt = 0; nt < 8; ++nt) {
        const int col = m + 16 * nt;
        biasr[nt] = (col < 64) ? b1[col] : b3[col - 64];
    }
    float b2v[4], b4v[2];
    #pragma unroll
    for (int c = 0; c < 4; ++c) b2v[c] = b2[c];
    #pragma unroll
    for (int c = 0; c < 2; ++c) b4v[c] = b4[c];

    // bias+relu, layer-2 partials, 16-lane butterfly reduce.
    // C layout: lane holds row 4*g + r, col m + 16*nt (reg r).
    float own[6] = {0.f, 0.f, 0.f, 0.f, 0.f, 0.f};
    #pragma unroll
    for (int r = 0; r < 4; ++r) {
        float v[6] = {0.f, 0.f, 0.f, 0.f, 0.f, 0.f};
        #pragma unroll
        for (int nt = 0; nt < 4; ++nt) {
            float h = fmaxf(acc[nt][r] + biasr[nt], 0.f);
            v[0] += h * w2r[nt][0];
            v[1] += h * w2r[nt][1];
            v[2] += h * w2r[nt][2];
            v[3] += h * w2r[nt][3];
        }
        #pragma unroll
        for (int j = 0; j < 4; ++j) {
            float h = fmaxf(acc[4 + j][r] + biasr[4 + j], 0.f);
            v[4] += h * w4r[j][0];
            v[5] += h * w4r[j][1];
        }
        #pragma unroll
        for (int msk = 1; msk <= 8; msk <<= 1) {
            #pragma unroll
            for (int c = 0; c < 6; ++c) v[c] += __shfl_xor(v[c], msk, 64);
        }
        if (m == r) {
            #pragma unroll
            for (int c = 0; c < 6; ++c) own[c] = v[c];
        }
    }

    // lanes m<4 finish one row each: sigmoid head + 2-class softmax
    if (m < 4) {
        const long row = rowBase + g * 4 + m;
        f32x4 pr = *(const f32x4*)(probs + row * 4);   // p00 p01 p10 p11
        float mu1[2], mu2[2], icv[2];
        #pragma unroll
        for (int c = 0; c < 2; ++c) {
            mu1[c] = 1.0f / (1.0f + __expf(-(own[c]     + b2v[c])));
            mu2[c] = 1.0f / (1.0f + __expf(-(own[2 + c] + b2v[2 + c])));
            icv[c] = 1.0f / (1.0f + __expf(-(own[4 + c] + b4v[c])));
        }
        float res[2];
        #pragma unroll
        for (int c = 0; c < 2; ++c) {
            float p0 = pr[c], p1 = pr[2 + c];
            float m12 = fminf(fmaxf(mu1[c], mu2[c]) + icv[c], 1.0f);
            res[c] = (p0 <= p1) ? (p0 * mu1[c] + (p1 - p0) * m12)
                                : (p1 * mu2[c] + (p0 - p1) * m12);
        }
        float d01 = res[0] - res[1];
        f32x2 o;
        o[0] = 1.0f / (1.0f + __expf(-d01));
        o[1] = 1.0f / (1.0f + __expf(d01));
        *(f32x2*)(out + row * 2) = o;
    }
}

extern "C" void kernel_launch(void* const* d_in, const int* in_sizes, int n_in,
                              void* d_out, int out_size, void* d_ws, size_t ws_size,
                              hipStream_t stream)
{
    const float* probs = (const float*)d_in[0];
    const float* x     = (const float*)d_in[1];
    const float* W1    = (const float*)d_in[2];
    const float* b1    = (const float*)d_in[3];
    const float* W2    = (const float*)d_in[4];
    const float* b2    = (const float*)d_in[5];
    const float* W3    = (const float*)d_in[6];
    const float* b3    = (const float*)d_in[7];
    const float* W4    = (const float*)d_in[8];
    const float* b4    = (const float*)d_in[9];
    float* out = (float*)d_out;
    short* bws = (short*)d_ws;   // 512*128 bf16 = 128 KiB

    hipLaunchKernelGGL(prep_weights, dim3(256), dim3(256), 0, stream, W1, W3, bws);
    hipLaunchKernelGGL(mf2_main, dim3(2048), dim3(512), 0, stream,
                       probs, x, bws, b1, W2, b2, b3, W4, b4, out);
}